// Round 1
// baseline (222.991 us; speedup 1.0000x reference)
//
#include <hip/hip_runtime.h>
#include <hip/hip_bf16.h>

typedef __attribute__((ext_vector_type(4))) float floatx4;
typedef __attribute__((ext_vector_type(8))) short short8;

#define HIDDEN 256
#define NOUT 16384   // GDIM*GDIM*GROUPS = 64*64*4

static __device__ __forceinline__ short bf16bits(float x) {
    __hip_bfloat16 h = __float2bfloat16(x);
    return __builtin_bit_cast(short, h);
}

#define GLDS16(gsrc, ldst) \
    __builtin_amdgcn_global_load_lds((const __attribute__((address_space(1))) void*)(gsrc), \
                                     (__attribute__((address_space(3))) void*)(ldst), 16, 0, 0)

// channel permutation: original channel c -> permuted position p (kB's fragment read order)
static __device__ __forceinline__ int permc(int c) {
    const int g = c >> 12, e = (c >> 6) & 63, d = c & 63;
    const int nt = e >> 4, lq = e & 15, ks = (d >> 5) & 1, quad = (d >> 3) & 3, j = d & 7;
    return ((((g << 2) | nt) << 1 | ks) << 9) | (((quad << 4) | lq) << 3) | j;
}
// inverse: permuted position p -> original channel c
static __device__ __forceinline__ int invperm(int p) {
    const int blk = p >> 9, g = blk >> 3, nt = (blk >> 1) & 3, ks = blk & 1;
    const int r = (p >> 3) & 63, quad = r >> 4, lq = r & 15, j = p & 7;
    return g * 4096 + (nt * 16 + lq) * 64 + ks * 32 + quad * 8 + j;
}

// ---------------- kPrep: Wg fp32 -> WgTp (bf16, transposed, channel-permuted); qc -> bf16 ----------------
__global__ __launch_bounds__(256) void kPrep(
    const float* __restrict__ Wg, short* __restrict__ WgTp,
    const float* __restrict__ qc, short* __restrict__ qcb, int n4)
{
    __shared__ short t[64 * 68];
    const int tid = threadIdx.x;

    if (blockIdx.x < 1024) {
        const int n0 = (blockIdx.x & 255) * 64, k0 = (blockIdx.x >> 8) * 64;
        // phase 1: coalesced read along n, write t[kl][nl] (bf16)
        const int r  = tid >> 4;
        const int c4 = tid & 15;
        #pragma unroll
        for (int i = 0; i < 4; ++i) {
            const int kl = r + i * 16;
            float4 f = *reinterpret_cast<const float4*>(Wg + (size_t)(k0 + kl) * NOUT + n0 + c4 * 4);
            short4 v;
            v.x = bf16bits(f.x); v.y = bf16bits(f.y); v.z = bf16bits(f.z); v.w = bf16bits(f.w);
            *reinterpret_cast<short4*>(&t[kl * 68 + c4 * 4]) = v;
        }
        __syncthreads();
        // phase 2: gather k-contiguous, b128 store to PERMUTED row
        #pragma unroll
        for (int h = 0; h < 2; ++h) {
            const int id = tid + h * 256;
            const int nl = id >> 3, kc = id & 7;
            short8 v;
            #pragma unroll
            for (int j = 0; j < 8; ++j) v[j] = t[(kc * 8 + j) * 68 + nl];
            const int prow = permc(n0 + nl);
            *reinterpret_cast<short8*>(WgTp + (size_t)prow * HIDDEN + k0 + kc * 8) = v;
        }
    } else {
        const int i = (blockIdx.x - 1024) * 256 + tid;
        if (i < n4) {
            float4 f = reinterpret_cast<const float4*>(qc)[i];
            short4 v;
            v.x = bf16bits(f.x); v.y = bf16bits(f.y); v.z = bf16bits(f.z); v.w = bf16bits(f.w);
            reinterpret_cast<short4*>(qcb)[i] = v;
        }
    }
}

// ---------------- kA5: wdyn_perm[M,16384] = bf16(qcb @ WgTp^T + bg∘inv) ----------------
// 128x128 tile, BK=64, 256 threads = 4 waves (2x2). Coalesced global_load_lds staging with
// source-side XOR swizzle; LDS-restaged epilogue for coalesced bf16 stores.
__global__ __launch_bounds__(256) void kA5(
    const short* __restrict__ qcb, const short* __restrict__ WgTp,
    const float* __restrict__ bg, short* __restrict__ wdyn, int M)
{
    __shared__ short As[128 * 64];   // 16 KB, [row][k-chunk^swz]
    __shared__ short Bs[128 * 64];   // 16 KB

    const int tid  = threadIdx.x;
    const int wave = tid >> 6, lane = tid & 63;
    const int lq   = lane & 15, quad = lane >> 4;
    const int wm   = wave >> 1, wn = wave & 1;
    const int m0   = blockIdx.x * 128;
    const int n0   = blockIdx.y * 128;

    // staging: 1024 16B-chunks per buffer per iter; 4 GLDS per thread per buffer.
    // LDS slot (row, c) holds global k-chunk (c ^ (row&7)) -> source carries the swizzle.
    const short* aSrc[4]; const short* bSrc[4];
    short* aDst[4]; short* bDst[4];
    #pragma unroll
    for (int t = 0; t < 4; ++t) {
        const int chunk = t * 256 + wave * 64 + lane;
        const int row = chunk >> 3, kc = chunk & 7;
        const int kcs = kc ^ (row & 7);
        int rA = m0 + row; if (rA >= M) rA = M - 1;
        aSrc[t] = qcb  + (size_t)rA * HIDDEN + kcs * 8;
        bSrc[t] = WgTp + (size_t)(n0 + row) * HIDDEN + kcs * 8;
        aDst[t] = &As[(t * 256 + wave * 64) * 8];   // wave-uniform; HW adds lane*16B
        bDst[t] = &Bs[(t * 256 + wave * 64) * 8];
    }

    // fragment LDS offsets (shorts), constant across iters
    int aOff[2][4], bOff[2][4];
    #pragma unroll
    for (int ks = 0; ks < 2; ++ks)
        #pragma unroll
        for (int i = 0; i < 4; ++i) {
            const int ra = wm * 64 + i * 16 + lq;
            aOff[ks][i] = ra * 64 + (((ks * 4 + quad) ^ (ra & 7)) * 8);
            const int rb = wn * 64 + i * 16 + lq;
            bOff[ks][i] = rb * 64 + (((ks * 4 + quad) ^ (rb & 7)) * 8);
        }

    floatx4 acc[4][4];
    #pragma unroll
    for (int i = 0; i < 4; ++i)
        #pragma unroll
        for (int j = 0; j < 4; ++j) acc[i][j] = (floatx4){0.f, 0.f, 0.f, 0.f};

    for (int it = 0; it < 4; ++it) {
        #pragma unroll
        for (int t = 0; t < 4; ++t) {
            GLDS16(aSrc[t], aDst[t]);
            GLDS16(bSrc[t], bDst[t]);
            aSrc[t] += 64; bSrc[t] += 64;
        }
        __syncthreads();

        #pragma unroll
        for (int ks = 0; ks < 2; ++ks) {
            short8 a[4], b[4];
            #pragma unroll
            for (int i = 0; i < 4; ++i) a[i] = *reinterpret_cast<const short8*>(&As[aOff[ks][i]]);
            #pragma unroll
            for (int j = 0; j < 4; ++j) b[j] = *reinterpret_cast<const short8*>(&Bs[bOff[ks][j]]);
            #pragma unroll
            for (int i = 0; i < 4; ++i)
                #pragma unroll
                for (int j = 0; j < 4; ++j)
                    acc[i][j] = __builtin_amdgcn_mfma_f32_16x16x32_bf16(a[i], b[j], acc[i][j], 0, 0, 0);
        }
        __syncthreads();
    }

    // bias via inverse channel permutation (bg is 64 KB, cache-resident)
    float bv[4];
    #pragma unroll
    for (int j = 0; j < 4; ++j) bv[j] = bg[invperm(n0 + wn * 64 + j * 16 + lq)];

    // epilogue: restage through LDS (reuse As as 64x128 bf16), coalesced stores
    short* Cs = As;
    #pragma unroll
    for (int half = 0; half < 2; ++half) {
        if (half) __syncthreads();
        if (wm == half) {
            #pragma unroll
            for (int j = 0; j < 4; ++j)
                #pragma unroll
                for (int i = 0; i < 4; ++i)
                    #pragma unroll
                    for (int r = 0; r < 4; ++r)
                        Cs[(i * 16 + quad * 4 + r) * 128 + wn * 64 + j * 16 + lq] =
                            bf16bits(acc[i][j][r] + bv[j]);
        }
        __syncthreads();
        #pragma unroll
        for (int t = 0; t < 4; ++t) {
            const int id = t * 256 + tid;
            const int mr = id >> 4, ch = id & 15;
            const int grow = m0 + half * 64 + mr;
            if (grow < M)
                *reinterpret_cast<short8*>(&wdyn[(size_t)grow * NOUT + n0 + ch * 8]) =
                    *reinterpret_cast<const short8*>(&Cs[mr * 128 + ch * 8]);
        }
    }
}

// ---------------- kB5: per (b,n): grouped mix + in-register LayerNorm + ReLU ----------------
// Transposed accumulator: mfma(w_frag, x_frag) gives D[c][p] (col=lane&15 <-> row p,
// reg r <-> consecutive channels). Each lane owns ONE output row p and 4-channel runs:
// float4 stores, 4-shfl LN reduction, float4 gamma/beta. All 24 global loads issued
// up-front for maximum memory-level parallelism (kernel is latency-bound: MfmaUtil 1.7%,
// VALUBusy 11%, HBM 44%, nothing saturated at VGPR=48).
__global__ __launch_bounds__(256) void kB5(
    const float* __restrict__ x, const short* __restrict__ wdyn,
    const float* __restrict__ gamma, const float* __restrict__ beta,
    float* __restrict__ out)
{
    __shared__ float red[2][2][16][2];   // [mtile][gp][lq][s/ss] = 512 B

    const int tid  = threadIdx.x;
    const int bnq  = blockIdx.x;
    const int wave = tid >> 6, lane = tid & 63;
    const int lq   = lane & 15, quad = lane >> 4;
    const int mtile = wave & 1, gp = wave >> 1;

    const float* xr = x + (size_t)bnq * (32 * HIDDEN) + (mtile * 16 + lq) * HIDDEN;
    const short* wr = wdyn + (size_t)bnq * NOUT + lane * 8;

    // issue x loads first (HBM, longest latency); fp32, nontemporal (streamed once)
    floatx4 xf[2][2][2];
    #pragma unroll
    for (int gi = 0; gi < 2; ++gi) {
        const int g = gp * 2 + gi;
        #pragma unroll
        for (int ks = 0; ks < 2; ++ks) {
            const floatx4* s = reinterpret_cast<const floatx4*>(xr + g * 64 + ks * 32 + quad * 8);
            xf[gi][ks][0] = __builtin_nontemporal_load(s);
            xf[gi][ks][1] = __builtin_nontemporal_load(s + 1);
        }
    }

    // issue ALL 16 wdyn fragment loads (L2/L3-resident, contiguous 1 KB per wave each)
    short8 bfr[2][2][4];
    #pragma unroll
    for (int gi = 0; gi < 2; ++gi) {
        const int g = gp * 2 + gi;
        #pragma unroll
        for (int ks = 0; ks < 2; ++ks)
            #pragma unroll
            for (int nt = 0; nt < 4; ++nt)
                bfr[gi][ks][nt] = *reinterpret_cast<const short8*>(
                    wr + (((((g << 2) | nt) << 1) | ks) << 9));
    }

    // convert x -> bf16 a-frags (waits only on x loads; wdyn loads stay in flight)
    short8 afr[2][2];
    #pragma unroll
    for (int gi = 0; gi < 2; ++gi)
        #pragma unroll
        for (int ks = 0; ks < 2; ++ks) {
            const floatx4 f0 = xf[gi][ks][0];
            const floatx4 f1 = xf[gi][ks][1];
            short8 v;
            v[0]=bf16bits(f0[0]); v[1]=bf16bits(f0[1]); v[2]=bf16bits(f0[2]); v[3]=bf16bits(f0[3]);
            v[4]=bf16bits(f1[0]); v[5]=bf16bits(f1[1]); v[6]=bf16bits(f1[2]); v[7]=bf16bits(f1[3]);
            afr[gi][ks] = v;
        }

    floatx4 acc[2][4];
    #pragma unroll
    for (int gi = 0; gi < 2; ++gi)
        #pragma unroll
        for (int nt = 0; nt < 4; ++nt) acc[gi][nt] = (floatx4){0.f, 0.f, 0.f, 0.f};

    // SWAPPED operands: D[c][p] — lane&15 = p, (lane>>4)*4+r = channel offset
    #pragma unroll
    for (int gi = 0; gi < 2; ++gi)
        #pragma unroll
        for (int ks = 0; ks < 2; ++ks)
            #pragma unroll
            for (int nt = 0; nt < 4; ++nt)
                acc[gi][nt] = __builtin_amdgcn_mfma_f32_16x16x32_bf16(
                    bfr[gi][ks][nt], afr[gi][ks], acc[gi][nt], 0, 0, 0);

    // LN reduction: each lane's 32 values all belong to row p = mtile*16+lq.
    float s = 0.f, ss = 0.f;
    #pragma unroll
    for (int gi = 0; gi < 2; ++gi)
        #pragma unroll
        for (int nt = 0; nt < 4; ++nt)
            #pragma unroll
            for (int r = 0; r < 4; ++r) {
                const float v = acc[gi][nt][r];
                s += v; ss += v * v;
            }
    // reduce across quads (same lq, 4 quads): 2 shfl per value
    s  += __shfl_xor(s, 16);  ss += __shfl_xor(ss, 16);
    s  += __shfl_xor(s, 32);  ss += __shfl_xor(ss, 32);

    if (quad == 0) { red[mtile][gp][lq][0] = s; red[mtile][gp][lq][1] = ss; }
    __syncthreads();

    const float S  = s  + red[mtile][gp ^ 1][lq][0];
    const float SS = ss + red[mtile][gp ^ 1][lq][1];
    const float mu = S * (1.f / 256.f);
    float var = SS * (1.f / 256.f) - mu * mu;
    var = fmaxf(var, 0.f);
    const float rs = rsqrtf(var + 1e-5f);

    // normalize + affine + relu: float4 per (gi,nt), nontemporal
    float* orow = out + (size_t)bnq * (32 * HIDDEN) + (mtile * 16 + lq) * HIDDEN;
    #pragma unroll
    for (int gi = 0; gi < 2; ++gi) {
        const int g = gp * 2 + gi;
        #pragma unroll
        for (int nt = 0; nt < 4; ++nt) {
            const int c0 = g * 64 + nt * 16 + quad * 4;
            const floatx4 gm = *reinterpret_cast<const floatx4*>(gamma + c0);
            const floatx4 bt = *reinterpret_cast<const floatx4*>(beta + c0);
            floatx4 o;
            #pragma unroll
            for (int r = 0; r < 4; ++r)
                o[r] = fmaxf((acc[gi][nt][r] - mu) * rs * gm[r] + bt[r], 0.f);
            __builtin_nontemporal_store(o, reinterpret_cast<floatx4*>(orow + c0));
        }
    }
}

extern "C" void kernel_launch(void* const* d_in, const int* in_sizes, int n_in,
                              void* d_out, int out_size, void* d_ws, size_t ws_size,
                              hipStream_t stream)
{
    const float* x     = (const float*)d_in[0];
    const float* qc    = (const float*)d_in[1];
    const float* Wg    = (const float*)d_in[2];
    const float* bg    = (const float*)d_in[3];
    const float* gamma = (const float*)d_in[4];
    const float* beta  = (const float*)d_in[5];
    float* out = (float*)d_out;

    const int M = in_sizes[1] / HIDDEN;   // B*N = 2400

    // workspace layout (bytes)
    char* ws = (char*)d_ws;
    short* wdyn = (short*)ws;                                    // M*16384*2
    short* WgTp = (short*)(ws + (size_t)M * NOUT * 2);           // 16384*256*2
    short* qcb  = (short*)(ws + (size_t)M * NOUT * 2 + (size_t)NOUT * HIDDEN * 2);

    const int n4 = (M * HIDDEN) / 4;
    const int prepBlocks = 1024 + (n4 + 255) / 256;
    kPrep<<<prepBlocks, 256, 0, stream>>>(Wg, WgTp, qc, qcb, n4);

    kA5<<<dim3((M + 127) / 128, NOUT / 128), 256, 0, stream>>>(qcb, WgTp, bg, wdyn, M);

    kB5<<<M, 256, 0, stream>>>(x, wdyn, gamma, beta, out);
}

// Round 2
// 217.342 us; speedup vs baseline: 1.0260x; 1.0260x over previous
//
#include <hip/hip_runtime.h>
#include <hip/hip_bf16.h>

typedef __attribute__((ext_vector_type(4))) float floatx4;
typedef __attribute__((ext_vector_type(8))) short short8;

#define HIDDEN 256
#define NOUT 16384   // GDIM*GDIM*GROUPS = 64*64*4

static __device__ __forceinline__ short bf16bits(float x) {
    __hip_bfloat16 h = __float2bfloat16(x);
    return __builtin_bit_cast(short, h);
}

#define GLDS16(gsrc, ldst) \
    __builtin_amdgcn_global_load_lds((const __attribute__((address_space(1))) void*)(gsrc), \
                                     (__attribute__((address_space(3))) void*)(ldst), 16, 0, 0)

// channel permutation: original channel c -> permuted position p (kB's fragment read order)
static __device__ __forceinline__ int permc(int c) {
    const int g = c >> 12, e = (c >> 6) & 63, d = c & 63;
    const int nt = e >> 4, lq = e & 15, ks = (d >> 5) & 1, quad = (d >> 3) & 3, j = d & 7;
    return ((((g << 2) | nt) << 1 | ks) << 9) | (((quad << 4) | lq) << 3) | j;
}
// inverse: permuted position p -> original channel c
static __device__ __forceinline__ int invperm(int p) {
    const int blk = p >> 9, g = blk >> 3, nt = (blk >> 1) & 3, ks = blk & 1;
    const int r = (p >> 3) & 63, quad = r >> 4, lq = r & 15, j = p & 7;
    return g * 4096 + (nt * 16 + lq) * 64 + ks * 32 + quad * 8 + j;
}

// ---------------- kPrep: Wg fp32 -> WgTp (bf16, transposed, channel-permuted); qc -> bf16 ----------------
__global__ __launch_bounds__(256) void kPrep(
    const float* __restrict__ Wg, short* __restrict__ WgTp,
    const float* __restrict__ qc, short* __restrict__ qcb, int n4)
{
    __shared__ short t[64 * 68];
    const int tid = threadIdx.x;

    if (blockIdx.x < 1024) {
        const int n0 = (blockIdx.x & 255) * 64, k0 = (blockIdx.x >> 8) * 64;
        // phase 1: coalesced read along n, write t[kl][nl] (bf16)
        const int r  = tid >> 4;
        const int c4 = tid & 15;
        #pragma unroll
        for (int i = 0; i < 4; ++i) {
            const int kl = r + i * 16;
            float4 f = *reinterpret_cast<const float4*>(Wg + (size_t)(k0 + kl) * NOUT + n0 + c4 * 4);
            short4 v;
            v.x = bf16bits(f.x); v.y = bf16bits(f.y); v.z = bf16bits(f.z); v.w = bf16bits(f.w);
            *reinterpret_cast<short4*>(&t[kl * 68 + c4 * 4]) = v;
        }
        __syncthreads();
        // phase 2: gather k-contiguous, b128 store to PERMUTED row
        #pragma unroll
        for (int h = 0; h < 2; ++h) {
            const int id = tid + h * 256;
            const int nl = id >> 3, kc = id & 7;
            short8 v;
            #pragma unroll
            for (int j = 0; j < 8; ++j) v[j] = t[(kc * 8 + j) * 68 + nl];
            const int prow = permc(n0 + nl);
            *reinterpret_cast<short8*>(WgTp + (size_t)prow * HIDDEN + k0 + kc * 8) = v;
        }
    } else {
        const int i = (blockIdx.x - 1024) * 256 + tid;
        if (i < n4) {
            float4 f = reinterpret_cast<const float4*>(qc)[i];
            short4 v;
            v.x = bf16bits(f.x); v.y = bf16bits(f.y); v.z = bf16bits(f.z); v.w = bf16bits(f.w);
            reinterpret_cast<short4*>(qcb)[i] = v;
        }
    }
}

// ---------------- kA5: wdyn_perm[M,16384] = bf16(qcb @ WgTp^T + bg∘inv) ----------------
// 128x128 tile, BK=64, 256 threads = 4 waves (2x2). Coalesced global_load_lds staging with
// source-side XOR swizzle; LDS-restaged epilogue for coalesced bf16 stores.
__global__ __launch_bounds__(256) void kA5(
    const short* __restrict__ qcb, const short* __restrict__ WgTp,
    const float* __restrict__ bg, short* __restrict__ wdyn, int M)
{
    __shared__ short As[128 * 64];   // 16 KB, [row][k-chunk^swz]
    __shared__ short Bs[128 * 64];   // 16 KB

    const int tid  = threadIdx.x;
    const int wave = tid >> 6, lane = tid & 63;
    const int lq   = lane & 15, quad = lane >> 4;
    const int wm   = wave >> 1, wn = wave & 1;
    const int m0   = blockIdx.x * 128;
    const int n0   = blockIdx.y * 128;

    // staging: 1024 16B-chunks per buffer per iter; 4 GLDS per thread per buffer.
    // LDS slot (row, c) holds global k-chunk (c ^ (row&7)) -> source carries the swizzle.
    const short* aSrc[4]; const short* bSrc[4];
    short* aDst[4]; short* bDst[4];
    #pragma unroll
    for (int t = 0; t < 4; ++t) {
        const int chunk = t * 256 + wave * 64 + lane;
        const int row = chunk >> 3, kc = chunk & 7;
        const int kcs = kc ^ (row & 7);
        int rA = m0 + row; if (rA >= M) rA = M - 1;
        aSrc[t] = qcb  + (size_t)rA * HIDDEN + kcs * 8;
        bSrc[t] = WgTp + (size_t)(n0 + row) * HIDDEN + kcs * 8;
        aDst[t] = &As[(t * 256 + wave * 64) * 8];   // wave-uniform; HW adds lane*16B
        bDst[t] = &Bs[(t * 256 + wave * 64) * 8];
    }

    // fragment LDS offsets (shorts), constant across iters
    int aOff[2][4], bOff[2][4];
    #pragma unroll
    for (int ks = 0; ks < 2; ++ks)
        #pragma unroll
        for (int i = 0; i < 4; ++i) {
            const int ra = wm * 64 + i * 16 + lq;
            aOff[ks][i] = ra * 64 + (((ks * 4 + quad) ^ (ra & 7)) * 8);
            const int rb = wn * 64 + i * 16 + lq;
            bOff[ks][i] = rb * 64 + (((ks * 4 + quad) ^ (rb & 7)) * 8);
        }

    floatx4 acc[4][4];
    #pragma unroll
    for (int i = 0; i < 4; ++i)
        #pragma unroll
        for (int j = 0; j < 4; ++j) acc[i][j] = (floatx4){0.f, 0.f, 0.f, 0.f};

    for (int it = 0; it < 4; ++it) {
        #pragma unroll
        for (int t = 0; t < 4; ++t) {
            GLDS16(aSrc[t], aDst[t]);
            GLDS16(bSrc[t], bDst[t]);
            aSrc[t] += 64; bSrc[t] += 64;
        }
        __syncthreads();

        #pragma unroll
        for (int ks = 0; ks < 2; ++ks) {
            short8 a[4], b[4];
            #pragma unroll
            for (int i = 0; i < 4; ++i) a[i] = *reinterpret_cast<const short8*>(&As[aOff[ks][i]]);
            #pragma unroll
            for (int j = 0; j < 4; ++j) b[j] = *reinterpret_cast<const short8*>(&Bs[bOff[ks][j]]);
            #pragma unroll
            for (int i = 0; i < 4; ++i)
                #pragma unroll
                for (int j = 0; j < 4; ++j)
                    acc[i][j] = __builtin_amdgcn_mfma_f32_16x16x32_bf16(a[i], b[j], acc[i][j], 0, 0, 0);
        }
        __syncthreads();
    }

    // bias via inverse channel permutation (bg is 64 KB, cache-resident)
    float bv[4];
    #pragma unroll
    for (int j = 0; j < 4; ++j) bv[j] = bg[invperm(n0 + wn * 64 + j * 16 + lq)];

    // epilogue: restage through LDS (reuse As as 64x128 bf16), coalesced stores
    short* Cs = As;
    #pragma unroll
    for (int half = 0; half < 2; ++half) {
        if (half) __syncthreads();
        if (wm == half) {
            #pragma unroll
            for (int j = 0; j < 4; ++j)
                #pragma unroll
                for (int i = 0; i < 4; ++i)
                    #pragma unroll
                    for (int r = 0; r < 4; ++r)
                        Cs[(i * 16 + quad * 4 + r) * 128 + wn * 64 + j * 16 + lq] =
                            bf16bits(acc[i][j][r] + bv[j]);
        }
        __syncthreads();
        #pragma unroll
        for (int t = 0; t < 4; ++t) {
            const int id = t * 256 + tid;
            const int mr = id >> 4, ch = id & 15;
            const int grow = m0 + half * 64 + mr;
            if (grow < M)
                *reinterpret_cast<short8*>(&wdyn[(size_t)grow * NOUT + n0 + ch * 8]) =
                    *reinterpret_cast<const short8*>(&Cs[mr * 128 + ch * 8]);
        }
    }
}

// ---------------- kB6: per (b,n): grouped mix + in-register LayerNorm + ReLU ----------------
// Swapped-operand MFMA (D[c][p], verified) for the cheap 2-shfl LN; low-VGPR load schedule
// (loads batched per (gi,ks), as in the 52-us kB4); output restaged through a 16 KB
// XOR-swizzled LDS buffer so global stores are fully contiguous 1 KB/wave nontemporal
// float4 streams (old path: 64 B scattered segments -> 3.5 of 6.3 TB/s).
__global__ __launch_bounds__(256) void kB6(
    const float* __restrict__ x, const short* __restrict__ wdyn,
    const float* __restrict__ gamma, const float* __restrict__ beta,
    float* __restrict__ out)
{
    __shared__ float ots[16 * 256];      // 16 KB epilogue restage (2 passes of 16 rows)
    __shared__ float red[2][2][16][2];   // [mtile][gp][lq][s/ss] = 512 B

    const int tid  = threadIdx.x;
    const int bnq  = blockIdx.x;
    const int wave = tid >> 6, lane = tid & 63;
    const int lq   = lane & 15, quad = lane >> 4;
    const int mtile = wave & 1, gp = wave >> 1;

    const float* xr = x + (size_t)bnq * (32 * HIDDEN) + (mtile * 16 + lq) * HIDDEN;
    const short* wr = wdyn + (size_t)bnq * NOUT + lane * 8;

    // x loads (HBM, longest latency): issue all 8, then convert
    floatx4 xf[2][2][2];
    #pragma unroll
    for (int gi = 0; gi < 2; ++gi) {
        const int g = gp * 2 + gi;
        #pragma unroll
        for (int ks = 0; ks < 2; ++ks) {
            const floatx4* s = reinterpret_cast<const floatx4*>(xr + g * 64 + ks * 32 + quad * 8);
            xf[gi][ks][0] = __builtin_nontemporal_load(s);
            xf[gi][ks][1] = __builtin_nontemporal_load(s + 1);
        }
    }
    short8 afr[2][2];
    #pragma unroll
    for (int gi = 0; gi < 2; ++gi)
        #pragma unroll
        for (int ks = 0; ks < 2; ++ks) {
            const floatx4 f0 = xf[gi][ks][0];
            const floatx4 f1 = xf[gi][ks][1];
            short8 v;
            v[0]=bf16bits(f0[0]); v[1]=bf16bits(f0[1]); v[2]=bf16bits(f0[2]); v[3]=bf16bits(f0[3]);
            v[4]=bf16bits(f1[0]); v[5]=bf16bits(f1[1]); v[6]=bf16bits(f1[2]); v[7]=bf16bits(f1[3]);
            afr[gi][ks] = v;
        }

    floatx4 acc[2][4];
    #pragma unroll
    for (int gi = 0; gi < 2; ++gi)
        #pragma unroll
        for (int nt = 0; nt < 4; ++nt) acc[gi][nt] = (floatx4){0.f, 0.f, 0.f, 0.f};

    // SWAPPED operands: D[c][p] — lane&15 = p, (lane>>4)*4+r = channel offset.
    // wdyn loads batched per (gi,ks): 4 in flight, low VGPR, compiler pipelines.
    #pragma unroll
    for (int gi = 0; gi < 2; ++gi) {
        const int g = gp * 2 + gi;
        #pragma unroll
        for (int ks = 0; ks < 2; ++ks) {
            short8 b[4];
            #pragma unroll
            for (int nt = 0; nt < 4; ++nt)
                b[nt] = *reinterpret_cast<const short8*>(
                    wr + (((((g << 2) | nt) << 1) | ks) << 9));
            #pragma unroll
            for (int nt = 0; nt < 4; ++nt)
                acc[gi][nt] = __builtin_amdgcn_mfma_f32_16x16x32_bf16(
                    b[nt], afr[gi][ks], acc[gi][nt], 0, 0, 0);
        }
    }

    // LN reduction: each lane's 32 values all belong to row p = mtile*16+lq.
    float s = 0.f, ss = 0.f;
    #pragma unroll
    for (int gi = 0; gi < 2; ++gi)
        #pragma unroll
        for (int nt = 0; nt < 4; ++nt)
            #pragma unroll
            for (int r = 0; r < 4; ++r) {
                const float v = acc[gi][nt][r];
                s += v; ss += v * v;
            }
    s  += __shfl_xor(s, 16);  ss += __shfl_xor(ss, 16);
    s  += __shfl_xor(s, 32);  ss += __shfl_xor(ss, 32);

    if (quad == 0) { red[mtile][gp][lq][0] = s; red[mtile][gp][lq][1] = ss; }
    __syncthreads();

    const float S  = s  + red[mtile][gp ^ 1][lq][0];
    const float SS = ss + red[mtile][gp ^ 1][lq][1];
    const float mu = S * (1.f / 256.f);
    float var = SS * (1.f / 256.f) - mu * mu;
    var = fmaxf(var, 0.f);
    const float rs = rsqrtf(var + 1e-5f);

    // normalize + affine + relu in place
    #pragma unroll
    for (int gi = 0; gi < 2; ++gi) {
        const int g = gp * 2 + gi;
        #pragma unroll
        for (int nt = 0; nt < 4; ++nt) {
            const int c0 = g * 64 + nt * 16 + quad * 4;
            const floatx4 gm = *reinterpret_cast<const floatx4*>(gamma + c0);
            const floatx4 bt = *reinterpret_cast<const floatx4*>(beta + c0);
            #pragma unroll
            for (int r = 0; r < 4; ++r)
                acc[gi][nt][r] = fmaxf((acc[gi][nt][r] - mu) * rs * gm[r] + bt[r], 0.f);
        }
    }

    // epilogue: two 16-row passes through swizzled LDS; fully coalesced global stores.
    // slot s = lq*64 + c4 (c4 = channel/4), stored at s ^ (lq&7): write inst spreads
    // bank-quartets uniformly ((nt*4+quad)^lq)&7; read inst has row const per wave.
    floatx4* ots4 = reinterpret_cast<floatx4*>(ots);
    floatx4* obase = reinterpret_cast<floatx4*>(out + (size_t)bnq * (32 * HIDDEN));
    #pragma unroll
    for (int h = 0; h < 2; ++h) {
        if (h) __syncthreads();
        if (mtile == h) {
            #pragma unroll
            for (int gi = 0; gi < 2; ++gi) {
                const int g = gp * 2 + gi;
                #pragma unroll
                for (int nt = 0; nt < 4; ++nt) {
                    const int c4 = g * 16 + nt * 4 + quad;
                    ots4[(lq * 64 + c4) ^ (lq & 7)] = acc[gi][nt];
                }
            }
        }
        __syncthreads();
        #pragma unroll
        for (int t = 0; t < 4; ++t) {
            const int sl = t * 256 + tid;
            const int pl = sl >> 6;                    // constant per wave
            const floatx4 v = ots4[sl ^ (pl & 7)];
            __builtin_nontemporal_store(v, obase + h * 1024 + sl);
        }
    }
}

extern "C" void kernel_launch(void* const* d_in, const int* in_sizes, int n_in,
                              void* d_out, int out_size, void* d_ws, size_t ws_size,
                              hipStream_t stream)
{
    const float* x     = (const float*)d_in[0];
    const float* qc    = (const float*)d_in[1];
    const float* Wg    = (const float*)d_in[2];
    const float* bg    = (const float*)d_in[3];
    const float* gamma = (const float*)d_in[4];
    const float* beta  = (const float*)d_in[5];
    float* out = (float*)d_out;

    const int M = in_sizes[1] / HIDDEN;   // B*N = 2400

    // workspace layout (bytes)
    char* ws = (char*)d_ws;
    short* wdyn = (short*)ws;                                    // M*16384*2
    short* WgTp = (short*)(ws + (size_t)M * NOUT * 2);           // 16384*256*2
    short* qcb  = (short*)(ws + (size_t)M * NOUT * 2 + (size_t)NOUT * HIDDEN * 2);

    const int n4 = (M * HIDDEN) / 4;
    const int prepBlocks = 1024 + (n4 + 255) / 256;
    kPrep<<<prepBlocks, 256, 0, stream>>>(Wg, WgTp, qc, qcb, n4);

    kA5<<<dim3((M + 127) / 128, NOUT / 128), 256, 0, stream>>>(qcb, WgTp, bg, wdyn, M);

    kB6<<<M, 256, 0, stream>>>(x, wdyn, gamma, beta, out);
}

// Round 3
// 217.158 us; speedup vs baseline: 1.0269x; 1.0008x over previous
//
#include <hip/hip_runtime.h>
#include <hip/hip_bf16.h>

typedef __attribute__((ext_vector_type(4))) float floatx4;
typedef __attribute__((ext_vector_type(8))) short short8;

#define HIDDEN 256
#define NOUT 16384   // GDIM*GDIM*GROUPS = 64*64*4

static __device__ __forceinline__ short bf16bits(float x) {
    __hip_bfloat16 h = __float2bfloat16(x);
    return __builtin_bit_cast(short, h);
}

// channel permutation: original channel c -> permuted position p (kB's fragment read order)
static __device__ __forceinline__ int permc(int c) {
    const int g = c >> 12, e = (c >> 6) & 63, d = c & 63;
    const int nt = e >> 4, lq = e & 15, ks = (d >> 5) & 1, quad = (d >> 3) & 3, j = d & 7;
    return ((((g << 2) | nt) << 1 | ks) << 9) | (((quad << 4) | lq) << 3) | j;
}
// inverse: permuted position p -> original channel c
static __device__ __forceinline__ int invperm(int p) {
    const int blk = p >> 9, g = blk >> 3, nt = (blk >> 1) & 3, ks = blk & 1;
    const int r = (p >> 3) & 63, quad = r >> 4, lq = r & 15, j = p & 7;
    return g * 4096 + (nt * 16 + lq) * 64 + ks * 32 + quad * 8 + j;
}

// ---------------- kPrep ----------------
// Wg fp32 -> WgF: bf16, transposed, channel-permuted AND fragment-tiled:
//   WgF[nT][q][lq][j]  (nT = prow>>4, lq = prow&15, k = q*8+j)
// so a wave's b-fragment load in kA is lane-contiguous 1 KB.
// qc fp32 -> qcF: bf16, same fragment tiling over rows.
__global__ __launch_bounds__(256) void kPrep(
    const float* __restrict__ Wg, short* __restrict__ WgF,
    const float* __restrict__ qc, short* __restrict__ qcF, int n4)
{
    __shared__ short t[64 * 68];
    const int tid = threadIdx.x;

    if (blockIdx.x < 1024) {
        const int n0 = (blockIdx.x & 255) * 64, k0 = (blockIdx.x >> 8) * 64;
        // phase 1: coalesced read along n, write t[kl][nl] (bf16)
        const int r  = tid >> 4;
        const int c4 = tid & 15;
        #pragma unroll
        for (int i = 0; i < 4; ++i) {
            const int kl = r + i * 16;
            float4 f = *reinterpret_cast<const float4*>(Wg + (size_t)(k0 + kl) * NOUT + n0 + c4 * 4);
            short4 v;
            v.x = bf16bits(f.x); v.y = bf16bits(f.y); v.z = bf16bits(f.z); v.w = bf16bits(f.w);
            *reinterpret_cast<short4*>(&t[kl * 68 + c4 * 4]) = v;
        }
        __syncthreads();
        // phase 2: gather k-contiguous, b128 store to fragment-tiled position
        #pragma unroll
        for (int h = 0; h < 2; ++h) {
            const int id = tid + h * 256;
            const int nl = id >> 3, kc = id & 7;
            short8 v;
            #pragma unroll
            for (int j = 0; j < 8; ++j) v[j] = t[(kc * 8 + j) * 68 + nl];
            const int prow = permc(n0 + nl);
            const int q = (k0 >> 3) + kc;            // k-chunk index 0..31
            *reinterpret_cast<short8*>(WgF + (size_t)(prow >> 4) * 4096 + q * 128 + (prow & 15) * 8) = v;
        }
    } else {
        const int i = (blockIdx.x - 1024) * 256 + tid;
        if (i < n4) {
            float4 f = reinterpret_cast<const float4*>(qc)[i];
            short4 v;
            v.x = bf16bits(f.x); v.y = bf16bits(f.y); v.z = bf16bits(f.z); v.w = bf16bits(f.w);
            const int m = i >> 6, k4 = i & 63;       // row, float4-index within row
            const int off = (m >> 4) * 4096 + (k4 >> 1) * 128 + (m & 15) * 8 + (k4 & 1) * 4;
            *reinterpret_cast<short4*>(qcF + off) = v;
        }
    }
}

// ---------------- kA6: wdyn_perm[M,16384] = bf16(qcF @ WgF^T + bg∘inv) ----------------
// Zero-LDS-staging GEMM: both operands are fragment-tiled so every A/B fragment load is a
// contiguous per-wave 1 KB dwordx4 straight to registers. No barriers / vmcnt(0) drains in
// the K-loop (the old 4-iter stage->drain->mfma structure was 97% stall: MfmaUtil 13%,
// occupancy 18%, 8.3 us wave lifetime for 0.3 us of compute). 2-deep ping-pong prefetch;
// compiler pipelines freely. XCD-aware remap: 8 XCDs x 16 B-panels x 19 m-blocks, so each
// XCD's 1 MB B-slice stays L2-resident across the m-sweep (old FETCH 53 MB = 8 XCDs
// re-fetching the whole 8 MB B; ideal ~9 MB).
__global__ __launch_bounds__(256) void kA6(
    const short* __restrict__ qcF, const short* __restrict__ WgF,
    const float* __restrict__ bg, short* __restrict__ wdyn, int M)
{
    __shared__ short Cs[64 * 128];   // 16 KB, epilogue restage only

    const int tid  = threadIdx.x;
    const int wave = tid >> 6, lane = tid & 63;
    const int lq   = lane & 15, quad = lane >> 4;
    const int wm   = wave >> 1, wn = wave & 1;

    // XCD-aware mapping: grid = nMB*128 blocks; wgid%8 ~ XCD (round-robin dispatch).
    const int wgid = blockIdx.x;
    const int xcd  = wgid & 7;
    const int c    = wgid >> 3;
    const int nMB  = gridDim.x >> 7;          // number of m-blocks (19)
    const int pl   = c / nMB;                 // panel-local index 0..15
    const int mi   = c - pl * nMB;            // m-block 0..nMB-1
    const int m0   = mi * 128;
    const int n0   = (xcd * 16 + pl) * 128;

    const int mtMax = M >> 4;                 // valid 16-row tiles (M % 16 == 0)
    const int mT0 = (m0 >> 4) + wm * 4;
    const int nT0 = (n0 >> 4) + wn * 4;

    const short* aB[4]; const short* bB[4];
    #pragma unroll
    for (int i = 0; i < 4; ++i) {
        int mT = mT0 + i; if (mT >= mtMax) mT = 0;   // clamp: garbage rows masked at store
        aB[i] = qcF + (size_t)mT * 4096 + lane * 8;
        bB[i] = WgF + (size_t)(nT0 + i) * 4096 + lane * 8;
    }

    floatx4 acc[4][4];
    #pragma unroll
    for (int i = 0; i < 4; ++i)
        #pragma unroll
        for (int j = 0; j < 4; ++j) acc[i][j] = (floatx4){0.f, 0.f, 0.f, 0.f};

    // K = 256 = 8 steps of 32; fragment for step: base + step*512 shorts (1 KB), lane*16B.
    short8 A[2][4], B[2][4];
    #pragma unroll
    for (int i = 0; i < 4; ++i) {
        A[0][i] = *reinterpret_cast<const short8*>(aB[i]);
        B[0][i] = *reinterpret_cast<const short8*>(bB[i]);
    }
    #pragma unroll
    for (int step = 0; step < 8; ++step) {
        const int cur = step & 1, nxt = cur ^ 1;
        if (step < 7) {
            #pragma unroll
            for (int i = 0; i < 4; ++i) {
                A[nxt][i] = *reinterpret_cast<const short8*>(aB[i] + (step + 1) * 512);
                B[nxt][i] = *reinterpret_cast<const short8*>(bB[i] + (step + 1) * 512);
            }
        }
        #pragma unroll
        for (int i = 0; i < 4; ++i)
            #pragma unroll
            for (int j = 0; j < 4; ++j)
                acc[i][j] = __builtin_amdgcn_mfma_f32_16x16x32_bf16(A[cur][i], B[cur][j], acc[i][j], 0, 0, 0);
    }

    // bias via inverse channel permutation (bg is 64 KB, cache-resident)
    float bv[4];
    #pragma unroll
    for (int j = 0; j < 4; ++j) bv[j] = bg[invperm(n0 + wn * 64 + j * 16 + lq)];

    // epilogue: restage through LDS (64x128 bf16), coalesced stores
    #pragma unroll
    for (int half = 0; half < 2; ++half) {
        if (half) __syncthreads();
        if (wm == half) {
            #pragma unroll
            for (int j = 0; j < 4; ++j)
                #pragma unroll
                for (int i = 0; i < 4; ++i)
                    #pragma unroll
                    for (int r = 0; r < 4; ++r)
                        Cs[(i * 16 + quad * 4 + r) * 128 + wn * 64 + j * 16 + lq] =
                            bf16bits(acc[i][j][r] + bv[j]);
        }
        __syncthreads();
        #pragma unroll
        for (int t = 0; t < 4; ++t) {
            const int id = t * 256 + tid;
            const int mr = id >> 4, ch = id & 15;
            const int grow = m0 + half * 64 + mr;
            if (grow < M)
                *reinterpret_cast<short8*>(&wdyn[(size_t)grow * NOUT + n0 + ch * 8]) =
                    *reinterpret_cast<const short8*>(&Cs[mr * 128 + ch * 8]);
        }
    }
}

// ---------------- kB6: per (b,n): grouped mix + in-register LayerNorm + ReLU ----------------
// Swapped-operand MFMA (D[c][p]) for the cheap 2-shfl LN; low-VGPR load schedule;
// output restaged through a 16 KB XOR-swizzled LDS buffer: fully contiguous 1 KB/wave
// nontemporal float4 store streams.
__global__ __launch_bounds__(256) void kB6(
    const float* __restrict__ x, const short* __restrict__ wdyn,
    const float* __restrict__ gamma, const float* __restrict__ beta,
    float* __restrict__ out)
{
    __shared__ float ots[16 * 256];      // 16 KB epilogue restage (2 passes of 16 rows)
    __shared__ float red[2][2][16][2];   // [mtile][gp][lq][s/ss] = 512 B

    const int tid  = threadIdx.x;
    const int bnq  = blockIdx.x;
    const int wave = tid >> 6, lane = tid & 63;
    const int lq   = lane & 15, quad = lane >> 4;
    const int mtile = wave & 1, gp = wave >> 1;

    const float* xr = x + (size_t)bnq * (32 * HIDDEN) + (mtile * 16 + lq) * HIDDEN;
    const short* wr = wdyn + (size_t)bnq * NOUT + lane * 8;

    // x loads (HBM, longest latency): issue all 8, then convert
    floatx4 xf[2][2][2];
    #pragma unroll
    for (int gi = 0; gi < 2; ++gi) {
        const int g = gp * 2 + gi;
        #pragma unroll
        for (int ks = 0; ks < 2; ++ks) {
            const floatx4* s = reinterpret_cast<const floatx4*>(xr + g * 64 + ks * 32 + quad * 8);
            xf[gi][ks][0] = __builtin_nontemporal_load(s);
            xf[gi][ks][1] = __builtin_nontemporal_load(s + 1);
        }
    }
    short8 afr[2][2];
    #pragma unroll
    for (int gi = 0; gi < 2; ++gi)
        #pragma unroll
        for (int ks = 0; ks < 2; ++ks) {
            const floatx4 f0 = xf[gi][ks][0];
            const floatx4 f1 = xf[gi][ks][1];
            short8 v;
            v[0]=bf16bits(f0[0]); v[1]=bf16bits(f0[1]); v[2]=bf16bits(f0[2]); v[3]=bf16bits(f0[3]);
            v[4]=bf16bits(f1[0]); v[5]=bf16bits(f1[1]); v[6]=bf16bits(f1[2]); v[7]=bf16bits(f1[3]);
            afr[gi][ks] = v;
        }

    floatx4 acc[2][4];
    #pragma unroll
    for (int gi = 0; gi < 2; ++gi)
        #pragma unroll
        for (int nt = 0; nt < 4; ++nt) acc[gi][nt] = (floatx4){0.f, 0.f, 0.f, 0.f};

    // SWAPPED operands: D[c][p] — lane&15 = p, (lane>>4)*4+r = channel offset.
    #pragma unroll
    for (int gi = 0; gi < 2; ++gi) {
        const int g = gp * 2 + gi;
        #pragma unroll
        for (int ks = 0; ks < 2; ++ks) {
            short8 b[4];
            #pragma unroll
            for (int nt = 0; nt < 4; ++nt)
                b[nt] = *reinterpret_cast<const short8*>(
                    wr + (((((g << 2) | nt) << 1) | ks) << 9));
            #pragma unroll
            for (int nt = 0; nt < 4; ++nt)
                acc[gi][nt] = __builtin_amdgcn_mfma_f32_16x16x32_bf16(
                    b[nt], afr[gi][ks], acc[gi][nt], 0, 0, 0);
        }
    }

    // LN reduction: each lane's 32 values all belong to row p = mtile*16+lq.
    float s = 0.f, ss = 0.f;
    #pragma unroll
    for (int gi = 0; gi < 2; ++gi)
        #pragma unroll
        for (int nt = 0; nt < 4; ++nt)
            #pragma unroll
            for (int r = 0; r < 4; ++r) {
                const float v = acc[gi][nt][r];
                s += v; ss += v * v;
            }
    s  += __shfl_xor(s, 16);  ss += __shfl_xor(ss, 16);
    s  += __shfl_xor(s, 32);  ss += __shfl_xor(ss, 32);

    if (quad == 0) { red[mtile][gp][lq][0] = s; red[mtile][gp][lq][1] = ss; }
    __syncthreads();

    const float S  = s  + red[mtile][gp ^ 1][lq][0];
    const float SS = ss + red[mtile][gp ^ 1][lq][1];
    const float mu = S * (1.f / 256.f);
    float var = SS * (1.f / 256.f) - mu * mu;
    var = fmaxf(var, 0.f);
    const float rs = rsqrtf(var + 1e-5f);

    // normalize + affine + relu in place
    #pragma unroll
    for (int gi = 0; gi < 2; ++gi) {
        const int g = gp * 2 + gi;
        #pragma unroll
        for (int nt = 0; nt < 4; ++nt) {
            const int c0 = g * 64 + nt * 16 + quad * 4;
            const floatx4 gm = *reinterpret_cast<const floatx4*>(gamma + c0);
            const floatx4 bt = *reinterpret_cast<const floatx4*>(beta + c0);
            #pragma unroll
            for (int r = 0; r < 4; ++r)
                acc[gi][nt][r] = fmaxf((acc[gi][nt][r] - mu) * rs * gm[r] + bt[r], 0.f);
        }
    }

    // epilogue: two 16-row passes through swizzled LDS; fully coalesced global stores.
    floatx4* ots4 = reinterpret_cast<floatx4*>(ots);
    floatx4* obase = reinterpret_cast<floatx4*>(out + (size_t)bnq * (32 * HIDDEN));
    #pragma unroll
    for (int h = 0; h < 2; ++h) {
        if (h) __syncthreads();
        if (mtile == h) {
            #pragma unroll
            for (int gi = 0; gi < 2; ++gi) {
                const int g = gp * 2 + gi;
                #pragma unroll
                for (int nt = 0; nt < 4; ++nt) {
                    const int c4 = g * 16 + nt * 4 + quad;
                    ots4[(lq * 64 + c4) ^ (lq & 7)] = acc[gi][nt];
                }
            }
        }
        __syncthreads();
        #pragma unroll
        for (int t = 0; t < 4; ++t) {
            const int sl = t * 256 + tid;
            const int pl = sl >> 6;                    // constant per wave
            const floatx4 v = ots4[sl ^ (pl & 7)];
            __builtin_nontemporal_store(v, obase + h * 1024 + sl);
        }
    }
}

extern "C" void kernel_launch(void* const* d_in, const int* in_sizes, int n_in,
                              void* d_out, int out_size, void* d_ws, size_t ws_size,
                              hipStream_t stream)
{
    const float* x     = (const float*)d_in[0];
    const float* qc    = (const float*)d_in[1];
    const float* Wg    = (const float*)d_in[2];
    const float* bg    = (const float*)d_in[3];
    const float* gamma = (const float*)d_in[4];
    const float* beta  = (const float*)d_in[5];
    float* out = (float*)d_out;

    const int M = in_sizes[1] / HIDDEN;   // B*N = 2400

    // workspace layout (bytes)
    char* ws = (char*)d_ws;
    short* wdyn = (short*)ws;                                    // M*16384*2
    short* WgF  = (short*)(ws + (size_t)M * NOUT * 2);           // 16384*256*2
    short* qcF  = (short*)(ws + (size_t)M * NOUT * 2 + (size_t)NOUT * HIDDEN * 2);

    const int n4 = (M * HIDDEN) / 4;
    const int prepBlocks = 1024 + (n4 + 255) / 256;
    kPrep<<<prepBlocks, 256, 0, stream>>>(Wg, WgF, qc, qcF, n4);

    const int nMB = (M + 127) / 128;      // 19
    kA6<<<nMB * 128, 256, 0, stream>>>(qcF, WgF, bg, wdyn, M);

    kB6<<<M, 256, 0, stream>>>(x, wdyn, gamma, beta, out);
}